// Round 4
// baseline (277.546 us; speedup 1.0000x reference)
//
#include <hip/hip_runtime.h>

typedef unsigned short u16;
typedef unsigned int u32;
typedef __attribute__((ext_vector_type(8))) __bf16 bf16x8;
typedef __attribute__((ext_vector_type(8))) _Float16 f16x8;
typedef __attribute__((ext_vector_type(4))) float f32x4;

// ---------- helpers ----------
__device__ __forceinline__ float b2f(u16 b) {
    union { u32 u; float f; } v; v.u = ((u32)b) << 16; return v.f;
}
__device__ __forceinline__ u16 f2bf(float f) {
    union { float f; u32 u; } v; v.f = f;
    u32 u = v.u;
    return (u16)((u + 0x7fffu + ((u >> 16) & 1u)) >> 16);  // RNE
}
__device__ __forceinline__ u16 f2h(float f) {
    _Float16 h = (_Float16)f;
    return __builtin_bit_cast(u16, h);
}
__device__ __forceinline__ bf16x8 ldg8b(const u16* p) {
    uint4 v = *(const uint4*)p;
    return __builtin_bit_cast(bf16x8, v);
}
__device__ __forceinline__ f16x8 ldg8h(const u16* p) {
    uint4 v = *(const uint4*)p;
    return __builtin_bit_cast(f16x8, v);
}
__device__ __forceinline__ f32x4 mfma_bf(bf16x8 a, bf16x8 b, f32x4 c) {
    return __builtin_amdgcn_mfma_f32_16x16x32_bf16(a, b, c, 0, 0, 0);
}
__device__ __forceinline__ f32x4 mfma_h(f16x8 a, f16x8 b, f32x4 c) {
    return __builtin_amdgcn_mfma_f32_16x16x32_f16(a, b, c, 0, 0, 0);
}

// Q global layout: per batch, row p (4096): 64 fp16, elem slot = d ^ ((p&7)*8)
// Gt global layout: per (n, step s of 64 p): 16384 elems: ch*64 + ((pp&~7)^((ch&7)*8)) + (pp&7)

// ---------- K0: hi/lo bf16 split of W, transposed: Wt[d][c] ----------
__global__ void k0_wt(const float* __restrict__ Wq,
                      u16* __restrict__ Wthi, u16* __restrict__ Wtlo) {
    int idx = blockIdx.x * 256 + threadIdx.x;   // 64 blocks -> 16384
    int c = idx >> 6, d = idx & 63;
    float w = Wq[idx];
    u16 hi = f2bf(w);
    float rem = w - b2f(hi);
    Wthi[d * 256 + c] = hi;
    Wtlo[d * 256 + c] = f2bf(rem);
}

// ---------- K1: Q = F*W (hi/lo split MFMA), fp16 out, XOR-swizzled rows ----------
__global__ __launch_bounds__(256) void k1_query(
    const float* __restrict__ F, const u16* __restrict__ Wthi,
    const u16* __restrict__ Wtlo, u16* __restrict__ Qh) {
    const int t = threadIdx.x;
    const int w = t >> 6, L = t & 63, lane16 = L & 15, quad = L >> 4;
    const int R0 = blockIdx.x * 64;
    const int row = R0 + w * 16 + lane16;
    const f32x4 z4 = {0.f, 0.f, 0.f, 0.f};
    f32x4 acc[4] = {z4, z4, z4, z4};
    union U8 { bf16x8 v; u16 s[8]; };
#pragma unroll
    for (int ks = 0; ks < 8; ++ks) {
        const float* fp = F + (size_t)row * 256 + ks * 32 + quad * 8;
        float4 x0 = *(const float4*)fp;
        float4 x1 = *(const float4*)(fp + 4);
        float xs[8] = {x0.x, x0.y, x0.z, x0.w, x1.x, x1.y, x1.z, x1.w};
        U8 ahi, alo;
#pragma unroll
        for (int j = 0; j < 8; ++j) {
            u16 h = f2bf(xs[j]);
            ahi.s[j] = h;
            alo.s[j] = f2bf(xs[j] - b2f(h));
        }
#pragma unroll
        for (int nt = 0; nt < 4; ++nt) {
            const int off = (nt * 16 + lane16) * 256 + ks * 32 + quad * 8;
            bf16x8 bh = ldg8b(Wthi + off);
            bf16x8 bl = ldg8b(Wtlo + off);
            acc[nt] = mfma_bf(ahi.v, bh, acc[nt]);
            acc[nt] = mfma_bf(alo.v, bh, acc[nt]);
            acc[nt] = mfma_bf(ahi.v, bl, acc[nt]);
        }
    }
    const int orow = R0 + w * 16 + quad * 4;
#pragma unroll
    for (int nt = 0; nt < 4; ++nt) {
        const int d = nt * 16 + lane16;
#pragma unroll
        for (int r = 0; r < 4; ++r) {
            const int p = orow + r;
            Qh[(size_t)p * 64 + (d ^ ((p & 7) << 3))] = f2h(acc[nt][r]);
        }
    }
}

// ---------- K2: inv_l[p] = 1 / sum_q exp(Q_p . Q_q), p-tile 32, grid 1024 ----------
__global__ __launch_bounds__(256) void k2_suminv(
    const u16* __restrict__ Q, float* __restrict__ inv_l) {
    const int t = threadIdx.x;
    const int w = t >> 6, L = t & 63, lane16 = L & 15, quad = L >> 4, l7 = lane16 & 7;
    const int bx = blockIdx.x;
    const int n = bx & 7, pb = bx >> 3;   // batch-per-XCD swizzle
    const int P0 = pb * 32;
    const u16* Qn = Q + (size_t)n * 4096 * 64;

    f16x8 ap[2][2];
#pragma unroll
    for (int st = 0; st < 2; ++st) {
        const int row = P0 + st * 16 + lane16;
        ap[st][0] = ldg8h(Qn + row * 64 + ((quad * 8) ^ (l7 * 8)));
        ap[st][1] = ldg8h(Qn + row * 64 + ((32 + quad * 8) ^ (l7 * 8)));
    }
    float sums[2][4];
#pragma unroll
    for (int st = 0; st < 2; ++st)
#pragma unroll
        for (int r = 0; r < 4; ++r) sums[st][r] = 0.f;

    const f32x4 z4 = {0.f, 0.f, 0.f, 0.f};
    for (int s = 0; s < 32; ++s) {
#pragma unroll
        for (int nt = 0; nt < 2; ++nt) {
            const int qr = w * 1024 + s * 32 + nt * 16 + lane16;
            f16x8 b0 = ldg8h(Qn + qr * 64 + ((quad * 8) ^ (l7 * 8)));
            f16x8 b1 = ldg8h(Qn + qr * 64 + ((32 + quad * 8) ^ (l7 * 8)));
#pragma unroll
            for (int st = 0; st < 2; ++st) {
                f32x4 z = z4;
                z = mfma_h(ap[st][0], b0, z);
                z = mfma_h(ap[st][1], b1, z);
                sums[st][0] += __expf(z[0]);
                sums[st][1] += __expf(z[1]);
                sums[st][2] += __expf(z[2]);
                sums[st][3] += __expf(z[3]);
            }
        }
    }
    __shared__ float red[4][32];
#pragma unroll
    for (int st = 0; st < 2; ++st)
#pragma unroll
        for (int r = 0; r < 4; ++r) {
            float v = sums[st][r];
            v += __shfl_xor(v, 1);
            v += __shfl_xor(v, 2);
            v += __shfl_xor(v, 4);
            v += __shfl_xor(v, 8);
            if (lane16 == 0) red[w][st * 16 + quad * 4 + r] = v;
        }
    __syncthreads();
    if (t < 32) {
        float tot = red[0][t] + red[1][t] + red[2][t] + red[3][t];
        inv_l[n * 4096 + P0 + t] = 1.0f / tot;
    }
}

// ---------- K3: Gt_sw[n][s][ch][p-swizzled] = bf16(F[n][p][ch]) ----------
__global__ __launch_bounds__(256) void k3_gt(
    const float* __restrict__ F, u16* __restrict__ Gt) {
    const int t = threadIdx.x;
    const int bx = blockIdx.x;                  // 512 = 8 n * 64 s
    const int n = bx >> 6, s = bx & 63;
    const int p0 = s * 64;
    __shared__ float tile[64][65];
    const float* Fn = F + (size_t)n * 4096 * 256;
    u16* Gn = Gt + (size_t)(n * 64 + s) * 16384;
#pragma unroll 1
    for (int ct = 0; ct < 4; ++ct) {
        const int c0 = ct * 64;
        if (ct > 0) __syncthreads();
#pragma unroll
        for (int k = 0; k < 16; ++k) {
            int idx = k * 256 + t;
            int r = idx >> 6, cc = idx & 63;
            tile[r][cc] = Fn[(size_t)(p0 + r) * 256 + c0 + cc];
        }
        __syncthreads();
#pragma unroll
        for (int k = 0; k < 2; ++k) {
            int u = k * 256 + t;
            int cc = u & 63, S = u >> 6;          // S in [0,8)
            int G = S ^ (cc & 7);
            u16 v[8];
#pragma unroll
            for (int j = 0; j < 8; ++j) v[j] = f2bf(tile[G * 8 + j][cc]);
            uint4 pk;
            pk.x = (u32)v[0] | ((u32)v[1] << 16);
            pk.y = (u32)v[2] | ((u32)v[3] << 16);
            pk.z = (u32)v[4] | ((u32)v[5] << 16);
            pk.w = (u32)v[6] | ((u32)v[7] << 16);
            *(uint4*)&Gn[(c0 + cc) * 64 + S * 8] = pk;
        }
    }
}

// ---------- K4: 64q x 256ch, p-step 64, register-direct operands,
//              single raw barrier per iter (LDS-only drain) ----------
__global__ __launch_bounds__(256, 2) void k4_attn(
    const u16* __restrict__ Q, const u16* __restrict__ Gt,
    const float* __restrict__ invl, const float* __restrict__ mask,
    const float* __restrict__ ref, float* __restrict__ out) {
    const int t = threadIdx.x;
    const int w = t >> 6, L = t & 63, lane16 = L & 15, quad = L >> 4, l7 = lane16 & 7;
    const int bx = blockIdx.x;
    const int n = bx & 7, qb = bx >> 3;   // batch-per-XCD swizzle
    const int q0 = qb << 6;

    __shared__ u16 sP[2][4096];   // P' 64q x 64p (swizzled), double-buffered

    const u16* Qn = Q + (size_t)n * 4096 * 64;
    const u16* Gtn = Gt + (size_t)n * 64 * 16384;
    const float* iln = invl + n * 4096;

    const int o0 = (quad * 8) ^ (l7 * 8);

    // invariant B-frags: this block's 64 q-rows of Q
    f16x8 bq[4][2];
#pragma unroll
    for (int qt = 0; qt < 4; ++qt) {
        const u16* r = Qn + (q0 + qt * 16 + lane16) * 64;
        bq[qt][0] = ldg8h(r + o0);
        bq[qt][1] = ldg8h(r + (o0 ^ 32));
    }

    // wave-private global bases
    const u16* qrow = Qn + (w * 16 + lane16) * 64;     // + i*4096 (+o0 / +o0^32)
    const u16* grow = Gtn + (w * 64 + lane16) * 64;    // + i*16384 + nt*1024 (+o0^(h*32))
    const float* ilp = iln + w * 16 + quad * 4;        // + i*64

    // sP write addresses (S-phase D-layout -> swizzled rows)
    int wrP[4];
#pragma unroll
    for (int qt = 0; qt < 4; ++qt)
        wrP[qt] = (qt * 16 + lane16) * 64 +
                  ((w * 16 + 8 * (quad >> 1)) ^ (l7 * 8)) + 4 * (quad & 1);

    const f32x4 z4 = {0.f, 0.f, 0.f, 0.f};
    f32x4 acc[4][4];
#pragma unroll
    for (int a = 0; a < 4; ++a)
#pragma unroll
        for (int b = 0; b < 4; ++b) acc[a][b] = z4;

    f16x8 qa0[2], qa1[2];
    float4 il[2];
    bf16x8 gb[8];

#define LOADSTEP(slot, step) do {                       \
        const u16* _q = qrow + (step) * 4096;           \
        qa0[slot] = ldg8h(_q + o0);                     \
        qa1[slot] = ldg8h(_q + (o0 ^ 32));              \
        il[slot] = *(const float4*)(ilp + (step) * 64); \
    } while (0)

#define LOADGB(step) do {                                   \
        const u16* _g = grow + (size_t)(step) * 16384;      \
        _Pragma("unroll")                                   \
        for (int nt = 0; nt < 4; ++nt) {                    \
            gb[nt * 2 + 0] = ldg8b(_g + nt * 1024 + o0);    \
            gb[nt * 2 + 1] = ldg8b(_g + nt * 1024 + (o0 ^ 32)); \
        }                                                   \
    } while (0)

#define ITER(i, cur, nxt) do {                                        \
        LOADGB(i);                                                    \
        if ((i) + 1 < 64) LOADSTEP(nxt, (i) + 1);                     \
        {   /* S phase: wave w, p-strip w, all 64 q */                \
            f16x8 a0 = qa0[cur], a1 = qa1[cur];                       \
            float4 il4 = il[cur];                                     \
            _Pragma("unroll")                                         \
            for (int qt = 0; qt < 4; ++qt) {                          \
                f32x4 z = z4;                                         \
                z = mfma_h(a0, bq[qt][0], z);                         \
                z = mfma_h(a1, bq[qt][1], z);                         \
                ushort4 pk;                                           \
                pk.x = f2bf(__expf(z[0]) * il4.x);                    \
                pk.y = f2bf(__expf(z[1]) * il4.y);                    \
                pk.z = f2bf(__expf(z[2]) * il4.z);                    \
                pk.w = f2bf(__expf(z[3]) * il4.w);                    \
                *(ushort4*)&sP[(i) & 1][wrP[qt]] = pk;                \
            }                                                         \
        }                                                             \
        asm volatile("s_waitcnt lgkmcnt(0)\n\ts_barrier" ::: "memory"); \
        _Pragma("unroll")                                             \
        for (int h = 0; h < 2; ++h) {   /* PV phase */                \
            bf16x8 af[4];                                             \
            _Pragma("unroll")                                         \
            for (int m = 0; m < 4; ++m)                               \
                af[m] = ldg8b(&sP[(i) & 1][(m * 16 + lane16) * 64 + (o0 ^ (h * 32))]); \
            _Pragma("unroll")                                         \
            for (int nt = 0; nt < 4; ++nt) {                          \
                _Pragma("unroll")                                     \
                for (int m = 0; m < 4; ++m)                           \
                    acc[m][nt] = mfma_bf(af[m], gb[nt * 2 + h], acc[m][nt]); \
            }                                                         \
        }                                                             \
    } while (0)

    // prologue: operands for step 0
    LOADSTEP(0, 0);

#pragma unroll 1
    for (int ii = 0; ii < 32; ++ii) {
        ITER(2 * ii, 0, 1);
        ITER(2 * ii + 1, 1, 0);
    }
#undef ITER
#undef LOADGB
#undef LOADSTEP

    // ---- epilogue: replicate the reference's reshape scramble ----
    // out pixel = ch*16 + (qb>>2), out channel = (qb&3)*64 + q_local
    const int tb = qb >> 2;
    const int cb = (qb & 3) * 64;
    const float* maskn = mask + n * 4096;
    const float* refn = ref + (size_t)n * 4096 * 256;
    float* outn = out + (size_t)n * 4096 * 512;
#pragma unroll
    for (int nt = 0; nt < 4; ++nt) {
        const int ch = w * 64 + nt * 16 + lane16;
        const int pixel = ch * 16 + tb;
        const float m = maskn[pixel];
#pragma unroll
        for (int mt = 0; mt < 4; ++mt) {
            const int c4 = cb + mt * 16 + quad * 4;
            float4 r4 = *(const float4*)(refn + (size_t)pixel * 256 + c4);
            float a0 = acc[mt][nt][0], a1 = acc[mt][nt][1];
            float a2 = acc[mt][nt][2], a3 = acc[mt][nt][3];
            float4 a4 = {a0, a1, a2, a3};
            float4 bl4 = {m * a0 + (1.f - m) * r4.x,
                          m * a1 + (1.f - m) * r4.y,
                          m * a2 + (1.f - m) * r4.z,
                          m * a3 + (1.f - m) * r4.w};
            *(float4*)(outn + (size_t)pixel * 512 + 256 + c4) = a4;   // src_att
            *(float4*)(outn + (size_t)pixel * 512 + c4) = bl4;        // ex_guide_flow
        }
    }
}

extern "C" void kernel_launch(void* const* d_in, const int* in_sizes, int n_in,
                              void* d_out, int out_size, void* d_ws, size_t ws_size,
                              hipStream_t stream) {
    const float* mask = (const float*)d_in[0];   // (8,64,64) f32
    const float* F    = (const float*)d_in[1];   // (8,64,64,256) f32
    const float* ref  = (const float*)d_in[2];   // (8,64,64,256) f32
    const float* Wq   = (const float*)d_in[3];   // (256,64) f32
    float* out = (float*)d_out;                  // (8,64,64,512) f32
    char* ws = (char*)d_ws;

    u16*   Wthi = (u16*)ws;                                     // 32 KB
    u16*   Wtlo = (u16*)(ws + 32768);                           // 32 KB
    u16*   Qh   = (u16*)(ws + 65536);                           // 4 MB (fp16, swizzled)
    float* invl = (float*)(ws + 65536 + 4194304);               // 128 KB
    u16*   Gt   = (u16*)(ws + 65536 + 4194304 + 131072);        // 16 MB (bf16, swizzled)

    k0_wt    <<<64,   256, 0, stream>>>(Wq, Wthi, Wtlo);
    k1_query <<<512,  256, 0, stream>>>(F, Wthi, Wtlo, Qh);
    k2_suminv<<<1024, 256, 0, stream>>>(Qh, invl);
    k3_gt    <<<512,  256, 0, stream>>>(F, Gt);
    k4_attn  <<<512,  256, 0, stream>>>(Qh, Gt, invl, mask, ref, out);
}